// Round 1
// baseline (241.903 us; speedup 1.0000x reference)
//
#include <hip/hip_runtime.h>

// Problem constants
#define LDIM 16384
#define KDIM 288
#define ODIM 64
#define BDIM 8

typedef float f32x4 __attribute__((ext_vector_type(4)));
typedef short bf16x8 __attribute__((ext_vector_type(8)));  // 8 bf16 in 4 VGPRs

// fp32 -> bf16 with round-to-nearest-even (bit trick; NaN irrelevant here)
__device__ __forceinline__ short f2bf(float f) {
  unsigned u = __builtin_bit_cast(unsigned, f);
  unsigned r = u + 0x7FFFu + ((u >> 16) & 1u);
  return (short)(r >> 16);
}

// ---------------------------------------------------------------------------
// Pre-kernel: swizzle W into MFMA B-fragment order (bf16) + cw[o] = -gamma*w2[o]
// wv[k][o] = w_flat[k*64 + o]  (memory reinterpretation per reference)
// B-fragment layout for mfma_f32_16x16x32_bf16:
//   frag elem j of lane ln, k-chunk kc, n-tile nt:
//   wfrag[((kc*4 + nt)*64 + ln)*8 + j] = bf16( wv[kc*32 + (ln>>4)*8 + j][nt*16 + (ln&15)] )
// ---------------------------------------------------------------------------
__global__ __launch_bounds__(256) void gauss_pre(const float* __restrict__ w,
                                                 const float* __restrict__ gammap,
                                                 short* __restrict__ wfrag,
                                                 float* __restrict__ cw) {
  int tid = threadIdx.x;

  // Part 1: fragment swizzle (9 kc * 4 nt * 64 lanes = 2304 fragments of 8)
  for (int f = tid; f < 9 * 256; f += 256) {
    int ln = f & 63;
    int nt = (f >> 6) & 3;
    int kc = f >> 8;
    int k0 = kc * 32 + (ln >> 4) * 8;
    int n = nt * 16 + (ln & 15);
    bf16x8 v;
#pragma unroll
    for (int j = 0; j < 8; ++j) v[j] = f2bf(w[(k0 + j) * 64 + n]);
    *(bf16x8*)(wfrag + f * 8) = v;
  }

  // Part 2: w2 reduction (256 threads: 4 segments of 72 k's per output col)
  __shared__ float red[256];
  int o = tid & 63;
  int seg = tid >> 6;
  float s = 0.f;
#pragma unroll 4
  for (int k = seg * 72; k < seg * 72 + 72; ++k) {
    float v = w[k * 64 + o];
    s += v * v;
  }
  red[tid] = s;
  __syncthreads();
  if (tid < 64) {
    float t = red[tid] + red[tid + 64] + red[tid + 128] + red[tid + 192];
    cw[tid] = -gammap[0] * t;
  }
}

// ---------------------------------------------------------------------------
// Main kernel: per-wave 32 rows x 64 cols GEMM via mfma_f32_16x16x32_bf16,
// register-direct A loads (no LDS, no barriers), fused RBF epilogue.
// Block = 256 threads (4 waves) = 128 rows. Grid = B*L/128 = 1024 blocks.
// ---------------------------------------------------------------------------
__global__ __launch_bounds__(256, 4) void gauss_main(
    const float* __restrict__ x, const short* __restrict__ wfrag,
    const float* __restrict__ cw, const float* __restrict__ bias,
    const float* __restrict__ gammap, float* __restrict__ out) {
  const int tid = threadIdx.x;
  const int lane = tid & 63;
  const int wvid = tid >> 6;
  const int m = lane & 15;     // A-row / C-col-helper index
  const int quad = lane >> 4;  // k-quad / C-row-group

  const long g0 = (long)blockIdx.x * 128;   // global row (b*L + l)
  const int bidx = (int)(g0 >> 14);         // L = 16384
  const int l0 = (int)(g0 & (LDIM - 1));

  const float gamma = gammap[0];

  // x[bidx][k][l] with l = l0 + wvid*32 + t*16 + m
  const float* xbase = x + (long)bidx * ((long)KDIM * LDIM) + (l0 + wvid * 32 + m);

  const f32x4 zero = {0.f, 0.f, 0.f, 0.f};
  f32x4 acc[2][4];
#pragma unroll
  for (int t = 0; t < 2; ++t)
#pragma unroll
    for (int nt = 0; nt < 4; ++nt) acc[t][nt] = zero;
  float s2[2] = {0.f, 0.f};  // per-lane partial |x|^2 for row m of each tile

#pragma unroll 1
  for (int kc = 0; kc < 9; ++kc) {
    // B fragments: 4 n-tiles, 16 B contiguous per lane (dwordx4, L2-hot)
    bf16x8 bfr[4];
    const short* wp = wfrag + ((kc * 4) * 64 + lane) * 8;
#pragma unroll
    for (int nt = 0; nt < 4; ++nt) bfr[nt] = *(const bf16x8*)(wp + nt * 512);

#pragma unroll
    for (int t = 0; t < 2; ++t) {
      // A fragment: lane holds x[k0+quad*8+j][l], 8 dword loads stride L
      const float* p = xbase + t * 16 + (long)(kc * 32 + quad * 8) * LDIM;
      float a[8];
#pragma unroll
      for (int j = 0; j < 8; ++j) a[j] = p[(long)j * LDIM];
      bf16x8 afr;
#pragma unroll
      for (int j = 0; j < 8; ++j) {
        s2[t] += a[j] * a[j];
        afr[j] = f2bf(a[j]);
      }
#pragma unroll
      for (int nt = 0; nt < 4; ++nt)
        acc[t][nt] =
            __builtin_amdgcn_mfma_f32_16x16x32_bf16(afr, bfr[nt], acc[t][nt], 0, 0, 0);
    }
  }

  // Finish |x|^2: butterfly across the 4 quads (lanes m, m+16, m+32, m+48)
#pragma unroll
  for (int t = 0; t < 2; ++t) {
    s2[t] += __shfl_xor(s2[t], 16, 64);
    s2[t] += __shfl_xor(s2[t], 32, 64);
  }

  // Per-column constants (L2-hot)
  float cwv[4], bv[4];
#pragma unroll
  for (int nt = 0; nt < 4; ++nt) {
    int col = nt * 16 + m;
    cwv[nt] = cw[col];   // -gamma * w2[o]
    bv[nt] = bias[col];  // b[o]
  }

  const float coef = 2.f * gamma;
  // Epilogue: C/D layout col = lane&15, row = quad*4 + r
#pragma unroll
  for (int t = 0; t < 2; ++t) {
#pragma unroll
    for (int r = 0; r < 4; ++r) {
      int row = quad * 4 + r;
      // fetch full |x|^2 for this C-row from the lane that owns it (same quad)
      float x2v = __shfl(s2[t], (lane & 48) | row, 64);
      float cx = -gamma * x2v;
      long grow = g0 + wvid * 32 + t * 16 + row;
      float* po = out + grow * 64 + m;
#pragma unroll
      for (int nt = 0; nt < 4; ++nt) {
        float e = coef * acc[t][nt][r] + (cx + cwv[nt]);  // -gamma*d2
        po[nt * 16] = __expf(e) + bv[nt];
      }
    }
  }
}

extern "C" void kernel_launch(void* const* d_in, const int* in_sizes, int n_in,
                              void* d_out, int out_size, void* d_ws, size_t ws_size,
                              hipStream_t stream) {
  const float* x = (const float*)d_in[0];      // [8, 288, 16384]
  const float* w = (const float*)d_in[1];      // [64, 32, 3, 3] -> flat 18432
  const float* b = (const float*)d_in[2];      // [64]
  const float* gamma = (const float*)d_in[3];  // scalar
  float* out = (float*)d_out;                  // [8, 16384, 64]

  short* wfrag = (short*)d_ws;                       // 18432 bf16 = 36864 B
  float* cw = (float*)((char*)d_ws + 36864);         // 64 floats

  gauss_pre<<<1, 256, 0, stream>>>(w, gamma, wfrag, cw);
  gauss_main<<<1024, 256, 0, stream>>>(x, wfrag, cw, b, gamma, out);
}